// Round 5
// baseline (260.295 us; speedup 1.0000x reference)
//
#include <hip/hip_runtime.h>
#include <hip/hip_bf16.h>

// MultiHeadSelfAttention: B=2, S=2048, D=1024, H=16, DK=64
// cast(f32->bf16) -> QKV gemm -> transpose V -> flash attention (XCD-local, KV-split) -> out-proj gemm

typedef __attribute__((ext_vector_type(4))) float f32x4;
typedef __attribute__((ext_vector_type(8))) short bf16x8;

__device__ __forceinline__ unsigned short f2bf(float f) {
  unsigned int u = __float_as_uint(f);
  u += 0x7fffu + ((u >> 16) & 1u);
  return (unsigned short)(u >> 16);
}
__device__ __forceinline__ float bf2f(unsigned short s) {
  return __uint_as_float(((unsigned int)s) << 16);
}

__global__ void cast_f32_bf16(const float* __restrict__ src,
                              unsigned short* __restrict__ dst, int n4) {
  int i = blockIdx.x * blockDim.x + threadIdx.x;
  if (i >= n4) return;
  float4 v = ((const float4*)src)[i];
  ushort4 o = make_ushort4(f2bf(v.x), f2bf(v.y), f2bf(v.z), f2bf(v.w));
  ((ushort4*)dst)[i] = o;
}

typedef __attribute__((address_space(1))) const void gas_t;
typedef __attribute__((address_space(3))) void las_t;

__device__ __forceinline__ void gld_lds16(const unsigned short* g, unsigned short* l) {
  __builtin_amdgcn_global_load_lds((gas_t*)g, (las_t*)l, 16, 0, 0);
}

// C = A (M,K) * B(N,K)^T ; bf16 in, bf16 or f32 out. m97 structure.
template<bool BF16OUT>
__global__ __launch_bounds__(256)
void gemm_bt(const unsigned short* __restrict__ A, const unsigned short* __restrict__ B,
             void* __restrict__ Cv, int M, int N, int K) {
  __shared__ unsigned short As[128 * 32];
  __shared__ unsigned short Bs[128 * 32];
  const int tid = threadIdx.x;
  const int lane = tid & 63;
  const int wid = tid >> 6;
  const int wr = wid >> 1, wc = wid & 1;
  const int lr = lane & 15, lg = lane >> 4;
  const int m0 = blockIdx.x * 128, n0 = blockIdx.y * 128;

  f32x4 acc[4][4] = {};

  const int srow = tid >> 2;
  const int scol = (tid & 3) * 8;
  const unsigned short* Ag = A + (size_t)(m0 + srow) * K + scol;
  const unsigned short* Bg = B + (size_t)(n0 + srow) * K + scol;
  unsigned short* Al = &As[tid * 8];
  unsigned short* Bl = &Bs[tid * 8];

  for (int k0 = 0; k0 < K; k0 += 32) {
    gld_lds16(Ag + k0, Al);
    gld_lds16(Ag + k0 + (size_t)64 * K, Al + 2048);
    gld_lds16(Bg + k0, Bl);
    gld_lds16(Bg + k0 + (size_t)64 * K, Bl + 2048);
    asm volatile("s_waitcnt vmcnt(0)" ::: "memory");
    __syncthreads();

    bf16x8 af[4], bfr[4];
#pragma unroll
    for (int i = 0; i < 4; ++i)
      af[i] = *(const bf16x8*)&As[(wr * 64 + i * 16 + lr) * 32 + lg * 8];
#pragma unroll
    for (int j = 0; j < 4; ++j)
      bfr[j] = *(const bf16x8*)&Bs[(wc * 64 + j * 16 + lr) * 32 + lg * 8];
#pragma unroll
    for (int i = 0; i < 4; ++i)
#pragma unroll
      for (int j = 0; j < 4; ++j)
        acc[i][j] = __builtin_amdgcn_mfma_f32_16x16x32_bf16(af[i], bfr[j], acc[i][j], 0, 0, 0);
    __syncthreads();
  }

#pragma unroll
  for (int i = 0; i < 4; ++i) {
    const int row = m0 + wr * 64 + i * 16 + lg * 4;
#pragma unroll
    for (int j = 0; j < 4; ++j) {
      const int col = n0 + wc * 64 + j * 16 + lr;
#pragma unroll
      for (int r = 0; r < 4; ++r) {
        float v = acc[i][j][r];
        size_t idx = (size_t)(row + r) * N + col;
        if (BF16OUT) ((unsigned short*)Cv)[idx] = f2bf(v);
        else         ((float*)Cv)[idx] = v;
      }
    }
  }
}

// VT[(bh*64 + d)*2048 + s] = QKV[(b*2048+s)*3072 + 2048 + h*64 + d]
__global__ __launch_bounds__(256)
void transpose_v(const unsigned short* __restrict__ QKV, unsigned short* __restrict__ VT) {
  __shared__ __align__(16) unsigned short t[64 * 64];
  const int tid = threadIdx.x;
  const int bh = blockIdx.y, b = bh >> 4, h = bh & 15;
  const int s0 = blockIdx.x * 64;
#pragma unroll
  for (int it = 0; it < 2; ++it) {
    int idx = it * 256 + tid;
    int r = idx >> 3, c8 = (idx & 7) * 8;
    bf16x8 v = *(const bf16x8*)(QKV + (size_t)(b * 2048 + s0 + r) * 3072 + 2048 + h * 64 + c8);
    int sw = ((r & 7) ^ ((r >> 3) & 7)) * 8;
    *(bf16x8*)&t[r * 64 + (c8 ^ sw)] = v;
  }
  __syncthreads();
#pragma unroll
  for (int it = 0; it < 2; ++it) {
    int idx = it * 256 + tid;
    int d = idx >> 3, s8 = (idx & 7) * 8;
    unsigned short tmp[8];
#pragma unroll
    for (int j = 0; j < 8; ++j) {
      int row = s8 + j;
      int sw = ((row & 7) ^ ((row >> 3) & 7)) * 8;
      tmp[j] = t[row * 64 + ((d & ~7) ^ sw) + (d & 7)];
    }
    *(bf16x8*)(VT + (size_t)(bh * 64 + d) * 2048 + s0 + s8) = *(bf16x8*)tmp;
  }
}

// Flash attention, causal, KVBLK=64, KV-split.
// Grid 2048: xcd=lb&7 (4 bh/XCD, KV stays L2-local); block = 4 waves:
//   (w0,w1) split q-tile p0's kv tiles, (w2,w3) split q-tile 127-p0's.
// Partials merged through a DEDICATED LDS buffer (96B/lane/sender, f32) —
// R4's bug was overlaying merge data on live P buffers (OOB + race).
__global__ __launch_bounds__(256, 3)
void attn5(const unsigned short* __restrict__ QKV, const unsigned short* __restrict__ VT,
           unsigned short* __restrict__ O) {
  const int tid = threadIdx.x;
  const int w = tid >> 6;
  const int lane = tid & 63;
  const int lr = lane & 15, lg = lane >> 4;
  const int lb = blockIdx.x;
  const int xcd = lb & 7;
  const int j = lb >> 3;               // 0..255
  const int bh = xcd * 4 + (j >> 6);   // 4 bh per XCD
  const int p0 = j & 63;
  const int b = bh >> 4, h = bh & 15;
  const int qp = (w < 2) ? p0 : (127 - p0);
  const int half = w & 1;
  const int nt = qp / 4 + 1;           // kv tiles of 64
  const int tmid = (nt + 1) >> 1;
  const int t0 = half ? tmid : 0;
  const int t1 = half ? nt : tmid;

  __shared__ __align__(16) unsigned short Pl[4][16 * 72];  // per-wave P staging
  __shared__ float Mrg[2][64 * 24];                        // merge: [sender][lane*24]
  unsigned short* P = Pl[w];

  const unsigned short* Qb = QKV + (size_t)b * 2048 * 3072 + h * 64;
  const unsigned short* Kb = QKV + (size_t)b * 2048 * 3072 + 1024 + h * 64;
  const unsigned short* Vt = VT + (size_t)bh * 64 * 2048;

  const float sc = 0.125f * 1.44269504088896f;  // 1/sqrt(64) * log2(e)

  bf16x8 qf[2];
  qf[0] = *(const bf16x8*)(Qb + (size_t)(qp * 16 + lr) * 3072 + lg * 8);
  qf[1] = *(const bf16x8*)(Qb + (size_t)(qp * 16 + lr) * 3072 + 32 + lg * 8);

  f32x4 o[4] = {};
  float Mr[4], Lr[4];
#pragma unroll
  for (int r = 0; r < 4; ++r) { Mr[r] = -1e30f; Lr[r] = 0.f; }

  bf16x8 kA[4][2], kB[4][2];

  auto loadK = [&](int t, bf16x8 (&kd)[4][2]) {
#pragma unroll
    for (int n = 0; n < 4; ++n)
#pragma unroll
      for (int c = 0; c < 2; ++c)
        kd[n][c] = *(const bf16x8*)(Kb + (size_t)(t * 64 + n * 16 + lr) * 3072 + c * 32 + lg * 8);
  };

  auto body = [&](int t, bf16x8 (&kcur)[4][2], bf16x8 (&knxt)[4][2]) {
    // --- S = Q K^T ---
    f32x4 s[4];
#pragma unroll
    for (int n = 0; n < 4; ++n) {
      s[n] = (f32x4){0.f, 0.f, 0.f, 0.f};
      s[n] = __builtin_amdgcn_mfma_f32_16x16x32_bf16(qf[0], kcur[n][0], s[n], 0, 0, 0);
      s[n] = __builtin_amdgcn_mfma_f32_16x16x32_bf16(qf[1], kcur[n][1], s[n], 0, 0, 0);
    }

    // --- V for this tile (latency hides under softmax) ---
    bf16x8 vf[4][2];
#pragma unroll
    for (int n = 0; n < 4; ++n)
#pragma unroll
      for (int c = 0; c < 2; ++c)
        vf[n][c] = *(const bf16x8*)(Vt + (size_t)(n * 16 + lr) * 2048 + t * 64 + c * 32 + lg * 8);

    // --- K prefetch for next tile (ping-pong, no reg copies) ---
    if (t + 1 < t1) loadK(t + 1, knxt);

    // --- scale (+ causal mask on diagonal tile), log2 domain ---
    float sv[4][4];
#pragma unroll
    for (int n = 0; n < 4; ++n)
#pragma unroll
      for (int r = 0; r < 4; ++r)
        sv[n][r] = s[n][r] * sc;
    if (t == nt - 1) {
#pragma unroll
      for (int n = 0; n < 4; ++n)
#pragma unroll
        for (int r = 0; r < 4; ++r) {
          int col = t * 64 + n * 16 + lr;
          int row = qp * 16 + lg * 4 + r;
          if (col > row) sv[n][r] = -3.0e38f;
        }
    }

    // --- online softmax with defer-max (THR=8, log2 domain) ---
    float mx[4];
#pragma unroll
    for (int r = 0; r < 4; ++r) {
      float m0 = fmaxf(fmaxf(sv[0][r], sv[1][r]), fmaxf(sv[2][r], sv[3][r]));
      m0 = fmaxf(m0, __shfl_xor(m0, 1));
      m0 = fmaxf(m0, __shfl_xor(m0, 2));
      m0 = fmaxf(m0, __shfl_xor(m0, 4));
      m0 = fmaxf(m0, __shfl_xor(m0, 8));
      mx[r] = m0;
    }
    bool changed = false;
    float mnew[4];
#pragma unroll
    for (int r = 0; r < 4; ++r) {
      mnew[r] = (mx[r] > Mr[r] + 8.0f) ? mx[r] : Mr[r];
      changed = changed || (mnew[r] != Mr[r]);
    }
    if (__any(changed)) {
#pragma unroll
      for (int r = 0; r < 4; ++r) {
        float ef = exp2f(Mr[r] - mnew[r]);
        Mr[r] = mnew[r];
        Lr[r] *= ef;
#pragma unroll
        for (int n = 0; n < 4; ++n) o[n][r] *= ef;
      }
    }
#pragma unroll
    for (int r = 0; r < 4; ++r) {
      float rs = 0.f;
#pragma unroll
      for (int n = 0; n < 4; ++n) {
        float p = exp2f(sv[n][r] - Mr[r]);
        sv[n][r] = p;
        rs += p;
      }
      Lr[r] += rs;   // lane-partial; reduced in epilogue
    }

    // --- P -> LDS (padded stride 72), reload as A-frags ---
#pragma unroll
    for (int n = 0; n < 4; ++n)
#pragma unroll
      for (int r = 0; r < 4; ++r)
        P[(lg * 4 + r) * 72 + n * 16 + lr] = f2bf(sv[n][r]);
    asm volatile("s_waitcnt lgkmcnt(0)" ::: "memory");
    bf16x8 pa[2];
    pa[0] = *(const bf16x8*)&P[lr * 72 + lg * 8];
    pa[1] = *(const bf16x8*)&P[lr * 72 + 32 + lg * 8];

    // --- O += P V ---
#pragma unroll
    for (int n = 0; n < 4; ++n) {
      o[n] = __builtin_amdgcn_mfma_f32_16x16x32_bf16(pa[0], vf[n][0], o[n], 0, 0, 0);
      o[n] = __builtin_amdgcn_mfma_f32_16x16x32_bf16(pa[1], vf[n][1], o[n], 0, 0, 0);
    }
  };

  if (t0 < t1) {
    loadK(t0, kA);
    int t = t0;
    while (true) {
      body(t, kA, kB);
      ++t; if (t >= t1) break;
      body(t, kB, kA);
      ++t; if (t >= t1) break;
    }
  }

  // --- merge the two kv-halves via dedicated LDS (f32) ---
  if (half) {
    float* mb = &Mrg[w >> 1][lane * 24];
#pragma unroll
    for (int n = 0; n < 4; ++n)
#pragma unroll
      for (int r = 0; r < 4; ++r)
        mb[n * 4 + r] = o[n][r];
#pragma unroll
    for (int r = 0; r < 4; ++r) { mb[16 + r] = Mr[r]; mb[20 + r] = Lr[r]; }
  }
  __syncthreads();
  if (!half) {
    const float* mb = &Mrg[w >> 1][lane * 24];
#pragma unroll
    for (int r = 0; r < 4; ++r) {
      float Mb = mb[16 + r], Lb = mb[20 + r];
      float M = fmaxf(Mr[r], Mb);
      float ea = exp2f(Mr[r] - M), eb = exp2f(Mb - M);
      Lr[r] = Lr[r] * ea + Lb * eb;
#pragma unroll
      for (int n = 0; n < 4; ++n)
        o[n][r] = o[n][r] * ea + mb[n * 4 + r] * eb;
    }
    // epilogue: reduce L across 16 row-lanes, write O/L
#pragma unroll
    for (int r = 0; r < 4; ++r) {
      float L = Lr[r];
      L += __shfl_xor(L, 1);
      L += __shfl_xor(L, 2);
      L += __shfl_xor(L, 4);
      L += __shfl_xor(L, 8);
      float inv = 1.0f / L;
      int row = qp * 16 + lg * 4 + r;
#pragma unroll
      for (int n = 0; n < 4; ++n) {
        float val = o[n][r] * inv;
        O[(size_t)(b * 2048 + row) * 1024 + h * 64 + n * 16 + lr] = f2bf(val);
      }
    }
  }
}

extern "C" void kernel_launch(void* const* d_in, const int* in_sizes, int n_in,
                              void* d_out, int out_size, void* d_ws, size_t ws_size,
                              hipStream_t stream) {
  const float* X  = (const float*)d_in[0];
  const float* Wq = (const float*)d_in[1];
  const float* Wk = (const float*)d_in[2];
  const float* Wv = (const float*)d_in[3];
  const float* Wo = (const float*)d_in[4];
  float* out = (float*)d_out;

  char* ws = (char*)d_ws;
  unsigned short* Xb    = (unsigned short*)(ws);                            // 8 MB (dead after QKV gemm)
  unsigned short* VTg   = (unsigned short*)(ws);                            // 8 MB (reuses Xb region)
  unsigned short* Wqkvb = (unsigned short*)(ws + (size_t)8  * 1024 * 1024); // 6 MB
  unsigned short* Wob   = (unsigned short*)(ws + (size_t)14 * 1024 * 1024); // 2 MB
  unsigned short* QKV   = (unsigned short*)(ws + (size_t)16 * 1024 * 1024); // 24 MB
  unsigned short* Ob    = (unsigned short*)(ws + (size_t)40 * 1024 * 1024); // 8 MB

  const int NX4 = (2 * 2048 * 1024) / 4;
  const int NW4 = (1024 * 1024) / 4;
  cast_f32_bf16<<<dim3((NX4 + 255) / 256), dim3(256), 0, stream>>>(X, Xb, NX4);
  cast_f32_bf16<<<dim3((NW4 + 255) / 256), dim3(256), 0, stream>>>(Wq, Wqkvb, NW4);
  cast_f32_bf16<<<dim3((NW4 + 255) / 256), dim3(256), 0, stream>>>(Wk, Wqkvb + 1024 * 1024, NW4);
  cast_f32_bf16<<<dim3((NW4 + 255) / 256), dim3(256), 0, stream>>>(Wv, Wqkvb + 2 * 1024 * 1024, NW4);
  cast_f32_bf16<<<dim3((NW4 + 255) / 256), dim3(256), 0, stream>>>(Wo, Wob, NW4);

  gemm_bt<true ><<<dim3(32, 24), dim3(256), 0, stream>>>(Xb, Wqkvb, (void*)QKV, 4096, 3072, 1024);
  transpose_v<<<dim3(32, 32), dim3(256), 0, stream>>>(QKV, VTg);
  attn5<<<dim3(2048), dim3(256), 0, stream>>>(QKV, VTg, Ob);
  gemm_bt<false><<<dim3(32, 8), dim3(256), 0, stream>>>(Ob, Wob, (void*)out, 4096, 1024, 1024);
}

// Round 6
// 159.317 us; speedup vs baseline: 1.6338x; 1.6338x over previous
//
#include <hip/hip_runtime.h>
#include <hip/hip_bf16.h>

// MultiHeadSelfAttention: B=2, S=2048, D=1024, H=16, DK=64
// cast(f32->bf16) -> QKV gemm -> transpose V -> flash attention (swapped-QKT, LDS-free) -> out-proj gemm

typedef __attribute__((ext_vector_type(4))) float f32x4;
typedef __attribute__((ext_vector_type(16))) float f32x16;
typedef __attribute__((ext_vector_type(8))) short bf16x8;

__device__ __forceinline__ unsigned short f2bf(float f) {
  unsigned int u = __float_as_uint(f);
  u += 0x7fffu + ((u >> 16) & 1u);
  return (unsigned short)(u >> 16);
}

__device__ __forceinline__ unsigned int cvtpk_bf16(float lo, float hi) {
  unsigned int r;
  asm("v_cvt_pk_bf16_f32 %0, %1, %2" : "=v"(r) : "v"(lo), "v"(hi));
  return r;
}

__global__ void cast_f32_bf16(const float* __restrict__ src,
                              unsigned short* __restrict__ dst, int n4) {
  int i = blockIdx.x * blockDim.x + threadIdx.x;
  if (i >= n4) return;
  float4 v = ((const float4*)src)[i];
  ushort4 o = make_ushort4(f2bf(v.x), f2bf(v.y), f2bf(v.z), f2bf(v.w));
  ((ushort4*)dst)[i] = o;
}

typedef __attribute__((address_space(1))) const void gas_t;
typedef __attribute__((address_space(3))) void las_t;

__device__ __forceinline__ void gld_lds16(const unsigned short* g, unsigned short* l) {
  __builtin_amdgcn_global_load_lds((gas_t*)g, (las_t*)l, 16, 0, 0);
}

// C = A (M,K) * B(N,K)^T ; bf16 in, bf16 or f32 out. m97 structure.
template<bool BF16OUT>
__global__ __launch_bounds__(256)
void gemm_bt(const unsigned short* __restrict__ A, const unsigned short* __restrict__ B,
             void* __restrict__ Cv, int M, int N, int K) {
  __shared__ unsigned short As[128 * 32];
  __shared__ unsigned short Bs[128 * 32];
  const int tid = threadIdx.x;
  const int lane = tid & 63;
  const int wid = tid >> 6;
  const int wr = wid >> 1, wc = wid & 1;
  const int lr = lane & 15, lg = lane >> 4;
  const int m0 = blockIdx.x * 128, n0 = blockIdx.y * 128;

  f32x4 acc[4][4] = {};

  const int srow = tid >> 2;
  const int scol = (tid & 3) * 8;
  const unsigned short* Ag = A + (size_t)(m0 + srow) * K + scol;
  const unsigned short* Bg = B + (size_t)(n0 + srow) * K + scol;
  unsigned short* Al = &As[tid * 8];
  unsigned short* Bl = &Bs[tid * 8];

  for (int k0 = 0; k0 < K; k0 += 32) {
    gld_lds16(Ag + k0, Al);
    gld_lds16(Ag + k0 + (size_t)64 * K, Al + 2048);
    gld_lds16(Bg + k0, Bl);
    gld_lds16(Bg + k0 + (size_t)64 * K, Bl + 2048);
    asm volatile("s_waitcnt vmcnt(0)" ::: "memory");
    __syncthreads();

    bf16x8 af[4], bfr[4];
#pragma unroll
    for (int i = 0; i < 4; ++i)
      af[i] = *(const bf16x8*)&As[(wr * 64 + i * 16 + lr) * 32 + lg * 8];
#pragma unroll
    for (int j = 0; j < 4; ++j)
      bfr[j] = *(const bf16x8*)&Bs[(wc * 64 + j * 16 + lr) * 32 + lg * 8];
#pragma unroll
    for (int i = 0; i < 4; ++i)
#pragma unroll
      for (int j = 0; j < 4; ++j)
        acc[i][j] = __builtin_amdgcn_mfma_f32_16x16x32_bf16(af[i], bfr[j], acc[i][j], 0, 0, 0);
    __syncthreads();
  }

#pragma unroll
  for (int i = 0; i < 4; ++i) {
    const int row = m0 + wr * 64 + i * 16 + lg * 4;
#pragma unroll
    for (int j = 0; j < 4; ++j) {
      const int col = n0 + wc * 64 + j * 16 + lr;
#pragma unroll
      for (int r = 0; r < 4; ++r) {
        float v = acc[i][j][r];
        size_t idx = (size_t)(row + r) * N + col;
        if (BF16OUT) ((unsigned short*)Cv)[idx] = f2bf(v);
        else         ((float*)Cv)[idx] = v;
      }
    }
  }
}

// VT[(bh*64 + d)*2048 + s] = QKV[(b*2048+s)*3072 + 2048 + h*64 + d]
__global__ __launch_bounds__(256)
void transpose_v(const unsigned short* __restrict__ QKV, unsigned short* __restrict__ VT) {
  __shared__ __align__(16) unsigned short t[64 * 64];
  const int tid = threadIdx.x;
  const int bh = blockIdx.y, b = bh >> 4, h = bh & 15;
  const int s0 = blockIdx.x * 64;
#pragma unroll
  for (int it = 0; it < 2; ++it) {
    int idx = it * 256 + tid;
    int r = idx >> 3, c8 = (idx & 7) * 8;
    bf16x8 v = *(const bf16x8*)(QKV + (size_t)(b * 2048 + s0 + r) * 3072 + 2048 + h * 64 + c8);
    int sw = ((r & 7) ^ ((r >> 3) & 7)) * 8;
    *(bf16x8*)&t[r * 64 + (c8 ^ sw)] = v;
  }
  __syncthreads();
#pragma unroll
  for (int it = 0; it < 2; ++it) {
    int idx = it * 256 + tid;
    int d = idx >> 3, s8 = (idx & 7) * 8;
    unsigned short tmp[8];
#pragma unroll
    for (int j = 0; j < 8; ++j) {
      int row = s8 + j;
      int sw = ((row & 7) ^ ((row >> 3) & 7)) * 8;
      tmp[j] = t[row * 64 + ((d & ~7) ^ sw) + (d & 7)];
    }
    *(bf16x8*)(VT + (size_t)(bh * 64 + d) * 2048 + s0 + s8) = *(bf16x8*)tmp;
  }
}

// Flash attention, causal, swapped-QKT 32x32, LDS-free, 1 wave/block.
// Grid 2048 x 64thr: qp = blk>>5 (q-tile of 32 rows), bh = blk&31.
//   XCD = blk&7 -> bh%8 -> 4 bh per XCD (KV 2MB, L2-resident);
//   CU c hosts qp in {c>>5 + 8k} -> balanced tile counts.
// S^T = mfma(K,Q): lane owns q-row (lane&31); softmax fully in-register.
// P -> bf16 via v_cvt_pk, A-frag assembly via shfl_xor(32)+select.
__global__ __launch_bounds__(64)
void attn6(const unsigned short* __restrict__ QKV, const unsigned short* __restrict__ VT,
           unsigned short* __restrict__ O) {
  const int lane = threadIdx.x;
  const int l31 = lane & 31;
  const int hi = lane >> 5;
  const int blk = blockIdx.x;
  const int qp = blk >> 5;   // 0..63
  const int bh = blk & 31;
  const int b = bh >> 4, h = bh & 15;
  const int nt = qp + 1;     // kv tiles of 32

  const unsigned short* Qb = QKV + (size_t)b * 2048 * 3072 + h * 64;
  const unsigned short* Kb = QKV + (size_t)b * 2048 * 3072 + 1024 + h * 64;
  const unsigned short* Vt = VT + (size_t)bh * 64 * 2048;

  const float sc = 0.125f * 1.44269504088896f;  // 1/sqrt(64) * log2(e)

  // Q as B-operand: col=q=l31, k-slice = 8*hi + e, d-chunk i*16
  bf16x8 qf[4];
#pragma unroll
  for (int i = 0; i < 4; ++i)
    qf[i] = *(const bf16x8*)(Qb + (size_t)(qp * 32 + l31) * 3072 + 16 * i + 8 * hi);

  f32x16 o0, o1;
#pragma unroll
  for (int r = 0; r < 16; ++r) { o0[r] = 0.f; o1[r] = 0.f; }
  float M = -1e30f, Lp = 0.f;

  bf16x8 kA[4], kB[4];

  auto loadK4 = [&](int t, bf16x8 (&kd)[4]) {
#pragma unroll
    for (int i = 0; i < 4; ++i)
      kd[i] = *(const bf16x8*)(Kb + (size_t)(t * 32 + l31) * 3072 + 16 * i + 8 * hi);
  };

  auto body = [&](int t, bf16x8 (&kcur)[4], bf16x8 (&knxt)[4]) {
    // --- S^T = K Q^T (32kv x 32q), lane owns q-col l31 ---
    f32x16 st;
#pragma unroll
    for (int r = 0; r < 16; ++r) st[r] = 0.f;
#pragma unroll
    for (int i = 0; i < 4; ++i)
      st = __builtin_amdgcn_mfma_f32_32x32x16_bf16(kcur[i], qf[i], st, 0, 0, 0);

    // --- V frags (B-operand for PV): row d = dh*32+l31, k = kv = c*16+8*hi+e ---
    bf16x8 vfr[2][2];
#pragma unroll
    for (int c = 0; c < 2; ++c)
#pragma unroll
      for (int dh = 0; dh < 2; ++dh)
        vfr[c][dh] = *(const bf16x8*)(Vt + (size_t)(dh * 32 + l31) * 2048 + t * 32 + c * 16 + 8 * hi);

    // --- K prefetch (ping-pong) ---
    if (t + 1 < nt) loadK4(t + 1, knxt);

    // --- scale (+ causal mask on diagonal), log2 domain ---
    float x[16];
#pragma unroll
    for (int r = 0; r < 16; ++r) x[r] = st[r] * sc;
    if (t == nt - 1) {
#pragma unroll
      for (int r = 0; r < 16; ++r) {
        int kvi = (r & 3) + 8 * (r >> 2) + 4 * hi;
        if (kvi > l31) x[r] = -3.0e38f;
      }
    }

    // --- row max (in-register) + cross-half ---
    float mx = x[0];
#pragma unroll
    for (int r = 1; r < 16; ++r) mx = fmaxf(mx, x[r]);
    mx = fmaxf(mx, __shfl_xor(mx, 32));

    // --- defer-max (THR=8): rescale only when max grows ---
    bool chg = mx > M + 8.0f;
    if (__any(chg)) {
      float Mn = chg ? mx : M;
      float ef = exp2f(M - Mn);
      M = Mn;
      Lp *= ef;
#pragma unroll
      for (int r = 0; r < 16; ++r) {
        int qr = (r & 3) + 8 * (r >> 2) + 4 * hi;
        float efb = __shfl(ef, qr);
        o0[r] *= efb;
        o1[r] *= efb;
      }
    }

    // --- P = exp2(x - M); lane-partial L ---
    float p[16];
    float rs = 0.f;
#pragma unroll
    for (int r = 0; r < 16; ++r) {
      p[r] = exp2f(x[r] - M);
      rs += p[r];
    }
    Lp += rs;

    // --- pack P to bf16 words; assemble PV A-frags via shfl_xor(32)+select ---
    unsigned int w[8];
#pragma unroll
    for (int g = 0; g < 4; ++g) {
      w[2 * g]     = cvtpk_bf16(p[4 * g],     p[4 * g + 1]);
      w[2 * g + 1] = cvtpk_bf16(p[4 * g + 2], p[4 * g + 3]);
    }
#pragma unroll
    for (int c = 0; c < 2; ++c) {
      unsigned int a0 = w[4 * c], a1 = w[4 * c + 1], b0 = w[4 * c + 2], b1 = w[4 * c + 3];
      unsigned int sa0 = __shfl_xor(a0, 32), sa1 = __shfl_xor(a1, 32);
      unsigned int sb0 = __shfl_xor(b0, 32), sb1 = __shfl_xor(b1, 32);
      union { unsigned int u[4]; bf16x8 v; } af;
      af.u[0] = hi ? sb0 : a0;   // e {0,1}
      af.u[1] = hi ? sb1 : a1;   // e {2,3}
      af.u[2] = hi ? b0  : sa0;  // e {4,5}
      af.u[3] = hi ? b1  : sa1;  // e {6,7}
      o0 = __builtin_amdgcn_mfma_f32_32x32x16_bf16(af.v, vfr[c][0], o0, 0, 0, 0);
      o1 = __builtin_amdgcn_mfma_f32_32x32x16_bf16(af.v, vfr[c][1], o1, 0, 0, 0);
    }
  };

  loadK4(0, kA);
  int t = 0;
  while (true) {
    body(t, kA, kB);
    ++t; if (t >= nt) break;
    body(t, kB, kA);
    ++t; if (t >= nt) break;
  }

  // --- epilogue: L across halves, broadcast invL to O-layout, store ---
  float Lt = Lp + __shfl_xor(Lp, 32);
  float inv = 1.0f / Lt;
#pragma unroll
  for (int r = 0; r < 16; ++r) {
    int qr = (r & 3) + 8 * (r >> 2) + 4 * hi;
    float ib = __shfl(inv, qr);
    size_t base = (size_t)(b * 2048 + qp * 32 + qr) * 1024 + h * 64;
    O[base + l31]      = f2bf(o0[r] * ib);
    O[base + 32 + l31] = f2bf(o1[r] * ib);
  }
}

extern "C" void kernel_launch(void* const* d_in, const int* in_sizes, int n_in,
                              void* d_out, int out_size, void* d_ws, size_t ws_size,
                              hipStream_t stream) {
  const float* X  = (const float*)d_in[0];
  const float* Wq = (const float*)d_in[1];
  const float* Wk = (const float*)d_in[2];
  const float* Wv = (const float*)d_in[3];
  const float* Wo = (const float*)d_in[4];
  float* out = (float*)d_out;

  char* ws = (char*)d_ws;
  unsigned short* Xb    = (unsigned short*)(ws);                            // 8 MB (dead after QKV gemm)
  unsigned short* VTg   = (unsigned short*)(ws);                            // 8 MB (reuses Xb region)
  unsigned short* Wqkvb = (unsigned short*)(ws + (size_t)8  * 1024 * 1024); // 6 MB
  unsigned short* Wob   = (unsigned short*)(ws + (size_t)14 * 1024 * 1024); // 2 MB
  unsigned short* QKV   = (unsigned short*)(ws + (size_t)16 * 1024 * 1024); // 24 MB
  unsigned short* Ob    = (unsigned short*)(ws + (size_t)40 * 1024 * 1024); // 8 MB

  const int NX4 = (2 * 2048 * 1024) / 4;
  const int NW4 = (1024 * 1024) / 4;
  cast_f32_bf16<<<dim3((NX4 + 255) / 256), dim3(256), 0, stream>>>(X, Xb, NX4);
  cast_f32_bf16<<<dim3((NW4 + 255) / 256), dim3(256), 0, stream>>>(Wq, Wqkvb, NW4);
  cast_f32_bf16<<<dim3((NW4 + 255) / 256), dim3(256), 0, stream>>>(Wk, Wqkvb + 1024 * 1024, NW4);
  cast_f32_bf16<<<dim3((NW4 + 255) / 256), dim3(256), 0, stream>>>(Wv, Wqkvb + 2 * 1024 * 1024, NW4);
  cast_f32_bf16<<<dim3((NW4 + 255) / 256), dim3(256), 0, stream>>>(Wo, Wob, NW4);

  gemm_bt<true ><<<dim3(32, 24), dim3(256), 0, stream>>>(Xb, Wqkvb, (void*)QKV, 4096, 3072, 1024);
  transpose_v<<<dim3(32, 32), dim3(256), 0, stream>>>(QKV, VTg);
  attn6<<<dim3(2048), dim3(64), 0, stream>>>(QKV, VTg, Ob);
  gemm_bt<false><<<dim3(32, 8), dim3(256), 0, stream>>>(Ob, Wob, (void*)out, 4096, 1024, 1024);
}

// Round 7
// 153.241 us; speedup vs baseline: 1.6986x; 1.0396x over previous
//
#include <hip/hip_runtime.h>
#include <hip/hip_bf16.h>

// MultiHeadSelfAttention: B=2, S=2048, D=1024, H=16, DK=64
// cast(f32->bf16) -> QKV gemm -> transpose V -> flash attention (swapped-QKT, paired-balanced) -> out-proj gemm

typedef __attribute__((ext_vector_type(4))) float f32x4;
typedef __attribute__((ext_vector_type(16))) float f32x16;
typedef __attribute__((ext_vector_type(8))) short bf16x8;

__device__ __forceinline__ unsigned short f2bf(float f) {
  unsigned int u = __float_as_uint(f);
  u += 0x7fffu + ((u >> 16) & 1u);
  return (unsigned short)(u >> 16);
}

__device__ __forceinline__ unsigned int cvtpk_bf16(float lo, float hi) {
  unsigned int r;
  asm("v_cvt_pk_bf16_f32 %0, %1, %2" : "=v"(r) : "v"(lo), "v"(hi));
  return r;
}

__global__ void cast_f32_bf16(const float* __restrict__ src,
                              unsigned short* __restrict__ dst, int n4) {
  int i = blockIdx.x * blockDim.x + threadIdx.x;
  if (i >= n4) return;
  float4 v = ((const float4*)src)[i];
  ushort4 o = make_ushort4(f2bf(v.x), f2bf(v.y), f2bf(v.z), f2bf(v.w));
  ((ushort4*)dst)[i] = o;
}

// Fused cast of the four weight matrices (each nw4 float4 elements).
__global__ void cast_w(const float* __restrict__ Wq, const float* __restrict__ Wk,
                       const float* __restrict__ Wv, const float* __restrict__ Wo,
                       unsigned short* __restrict__ Wqkvb, unsigned short* __restrict__ Wob,
                       int nw4) {
  int i = blockIdx.x * blockDim.x + threadIdx.x;
  int sel = i / nw4, r = i - sel * nw4;
  if (sel >= 4) return;
  const float* src = (sel == 0) ? Wq : (sel == 1) ? Wk : (sel == 2) ? Wv : Wo;
  unsigned short* dst = (sel < 3) ? (Wqkvb + (size_t)sel * 1024 * 1024) : Wob;
  float4 v = ((const float4*)src)[r];
  ushort4 o = make_ushort4(f2bf(v.x), f2bf(v.y), f2bf(v.z), f2bf(v.w));
  ((ushort4*)dst)[r] = o;
}

typedef __attribute__((address_space(1))) const void gas_t;
typedef __attribute__((address_space(3))) void las_t;

__device__ __forceinline__ void gld_lds16(const unsigned short* g, unsigned short* l) {
  __builtin_amdgcn_global_load_lds((gas_t*)g, (las_t*)l, 16, 0, 0);
}

// C = A (M,K) * B(N,K)^T ; bf16 in, bf16 or f32 out. m97 structure.
template<bool BF16OUT>
__global__ __launch_bounds__(256)
void gemm_bt(const unsigned short* __restrict__ A, const unsigned short* __restrict__ B,
             void* __restrict__ Cv, int M, int N, int K) {
  __shared__ unsigned short As[128 * 32];
  __shared__ unsigned short Bs[128 * 32];
  const int tid = threadIdx.x;
  const int lane = tid & 63;
  const int wid = tid >> 6;
  const int wr = wid >> 1, wc = wid & 1;
  const int lr = lane & 15, lg = lane >> 4;
  const int m0 = blockIdx.x * 128, n0 = blockIdx.y * 128;

  f32x4 acc[4][4] = {};

  const int srow = tid >> 2;
  const int scol = (tid & 3) * 8;
  const unsigned short* Ag = A + (size_t)(m0 + srow) * K + scol;
  const unsigned short* Bg = B + (size_t)(n0 + srow) * K + scol;
  unsigned short* Al = &As[tid * 8];
  unsigned short* Bl = &Bs[tid * 8];

  for (int k0 = 0; k0 < K; k0 += 32) {
    gld_lds16(Ag + k0, Al);
    gld_lds16(Ag + k0 + (size_t)64 * K, Al + 2048);
    gld_lds16(Bg + k0, Bl);
    gld_lds16(Bg + k0 + (size_t)64 * K, Bl + 2048);
    asm volatile("s_waitcnt vmcnt(0)" ::: "memory");
    __syncthreads();

    bf16x8 af[4], bfr[4];
#pragma unroll
    for (int i = 0; i < 4; ++i)
      af[i] = *(const bf16x8*)&As[(wr * 64 + i * 16 + lr) * 32 + lg * 8];
#pragma unroll
    for (int j = 0; j < 4; ++j)
      bfr[j] = *(const bf16x8*)&Bs[(wc * 64 + j * 16 + lr) * 32 + lg * 8];
#pragma unroll
    for (int i = 0; i < 4; ++i)
#pragma unroll
      for (int j = 0; j < 4; ++j)
        acc[i][j] = __builtin_amdgcn_mfma_f32_16x16x32_bf16(af[i], bfr[j], acc[i][j], 0, 0, 0);
    __syncthreads();
  }

#pragma unroll
  for (int i = 0; i < 4; ++i) {
    const int row = m0 + wr * 64 + i * 16 + lg * 4;
#pragma unroll
    for (int j = 0; j < 4; ++j) {
      const int col = n0 + wc * 64 + j * 16 + lr;
#pragma unroll
      for (int r = 0; r < 4; ++r) {
        float v = acc[i][j][r];
        size_t idx = (size_t)(row + r) * N + col;
        if (BF16OUT) ((unsigned short*)Cv)[idx] = f2bf(v);
        else         ((float*)Cv)[idx] = v;
      }
    }
  }
}

// VT[(bh*64 + d)*2048 + s] = QKV[(b*2048+s)*3072 + 2048 + h*64 + d]
__global__ __launch_bounds__(256)
void transpose_v(const unsigned short* __restrict__ QKV, unsigned short* __restrict__ VT) {
  __shared__ __align__(16) unsigned short t[64 * 64];
  const int tid = threadIdx.x;
  const int bh = blockIdx.y, b = bh >> 4, h = bh & 15;
  const int s0 = blockIdx.x * 64;
#pragma unroll
  for (int it = 0; it < 2; ++it) {
    int idx = it * 256 + tid;
    int r = idx >> 3, c8 = (idx & 7) * 8;
    bf16x8 v = *(const bf16x8*)(QKV + (size_t)(b * 2048 + s0 + r) * 3072 + 2048 + h * 64 + c8);
    int sw = ((r & 7) ^ ((r >> 3) & 7)) * 8;
    *(bf16x8*)&t[r * 64 + (c8 ^ sw)] = v;
  }
  __syncthreads();
#pragma unroll
  for (int it = 0; it < 2; ++it) {
    int idx = it * 256 + tid;
    int d = idx >> 3, s8 = (idx & 7) * 8;
    unsigned short tmp[8];
#pragma unroll
    for (int j = 0; j < 8; ++j) {
      int row = s8 + j;
      int sw = ((row & 7) ^ ((row >> 3) & 7)) * 8;
      tmp[j] = t[row * 64 + ((d & ~7) ^ sw) + (d & 7)];
    }
    *(bf16x8*)(VT + (size_t)(bh * 64 + d) * 2048 + s0 + s8) = *(bf16x8*)tmp;
  }
}

// Flash attention, causal, swapped-QKT 32x32, LDS-free, 1 wave/block.
// Balanced: wave handles qp = pair AND qp = 63-pair -> exactly 65 kv-tiles each.
// Grid 1024 = 32 pairs x 32 bh (bh in low bits: 4 bh/XCD, KV L2-resident).
__global__ __launch_bounds__(64)
void attn7(const unsigned short* __restrict__ QKV, const unsigned short* __restrict__ VT,
           unsigned short* __restrict__ O) {
  const int lane = threadIdx.x;
  const int l31 = lane & 31;
  const int hi = lane >> 5;
  const int blk = blockIdx.x;
  const int pair = blk >> 5;  // 0..31
  const int bh = blk & 31;
  const int b = bh >> 4, h = bh & 15;

  const unsigned short* Qb = QKV + (size_t)b * 2048 * 3072 + h * 64;
  const unsigned short* Kb = QKV + (size_t)b * 2048 * 3072 + 1024 + h * 64;
  const unsigned short* Vt = VT + (size_t)bh * 64 * 2048;

  const float sc = 0.125f * 1.44269504088896f;  // 1/sqrt(64) * log2(e)

  for (int ph = 0; ph < 2; ++ph) {
    const int qp = ph ? (63 - pair) : pair;
    const int nt = qp + 1;  // kv tiles of 32

    // Q as B-operand: col=q=l31, k-slice = 8*hi + e, d-chunk i*16
    bf16x8 qf[4];
#pragma unroll
    for (int i = 0; i < 4; ++i)
      qf[i] = *(const bf16x8*)(Qb + (size_t)(qp * 32 + l31) * 3072 + 16 * i + 8 * hi);

    f32x16 o0, o1;
#pragma unroll
    for (int r = 0; r < 16; ++r) { o0[r] = 0.f; o1[r] = 0.f; }
    float M = -1e30f, Lp = 0.f;

    bf16x8 kA[4], kB[4];

    auto loadK4 = [&](int t, bf16x8 (&kd)[4]) {
#pragma unroll
      for (int i = 0; i < 4; ++i)
        kd[i] = *(const bf16x8*)(Kb + (size_t)(t * 32 + l31) * 3072 + 16 * i + 8 * hi);
    };

    auto body = [&](int t, bf16x8 (&kcur)[4], bf16x8 (&knxt)[4]) {
      // --- S^T = K Q^T (32kv x 32q), lane owns q-col l31 ---
      f32x16 st;
#pragma unroll
      for (int r = 0; r < 16; ++r) st[r] = 0.f;
#pragma unroll
      for (int i = 0; i < 4; ++i)
        st = __builtin_amdgcn_mfma_f32_32x32x16_bf16(kcur[i], qf[i], st, 0, 0, 0);

      // --- V frags (B-operand for PV): row d = dh*32+l31, k = kv = c*16+8*hi+e ---
      bf16x8 vfr[2][2];
#pragma unroll
      for (int c = 0; c < 2; ++c)
#pragma unroll
        for (int dh = 0; dh < 2; ++dh)
          vfr[c][dh] = *(const bf16x8*)(Vt + (size_t)(dh * 32 + l31) * 2048 + t * 32 + c * 16 + 8 * hi);

      // --- K prefetch (ping-pong) ---
      if (t + 1 < nt) loadK4(t + 1, knxt);

      // --- scale (+ causal mask on diagonal), log2 domain ---
      float x[16];
#pragma unroll
      for (int r = 0; r < 16; ++r) x[r] = st[r] * sc;
      if (t == nt - 1) {
#pragma unroll
        for (int r = 0; r < 16; ++r) {
          int kvi = (r & 3) + 8 * (r >> 2) + 4 * hi;
          if (kvi > l31) x[r] = -3.0e38f;
        }
      }

      // --- row max (in-register) + cross-half ---
      float mx = x[0];
#pragma unroll
      for (int r = 1; r < 16; ++r) mx = fmaxf(mx, x[r]);
      mx = fmaxf(mx, __shfl_xor(mx, 32));

      // --- defer-max (THR=8): rescale only when max grows ---
      bool chg = mx > M + 8.0f;
      if (__any(chg)) {
        float Mn = chg ? mx : M;
        float ef = exp2f(M - Mn);
        M = Mn;
        Lp *= ef;
#pragma unroll
        for (int r = 0; r < 16; ++r) {
          int qr = (r & 3) + 8 * (r >> 2) + 4 * hi;
          float efb = __shfl(ef, qr);
          o0[r] *= efb;
          o1[r] *= efb;
        }
      }

      // --- P = exp2(x - M); lane-partial L ---
      float p[16];
      float rs = 0.f;
#pragma unroll
      for (int r = 0; r < 16; ++r) {
        p[r] = exp2f(x[r] - M);
        rs += p[r];
      }
      Lp += rs;

      // --- pack P to bf16 words; assemble PV A-frags via shfl_xor(32)+select ---
      unsigned int w[8];
#pragma unroll
      for (int g = 0; g < 4; ++g) {
        w[2 * g]     = cvtpk_bf16(p[4 * g],     p[4 * g + 1]);
        w[2 * g + 1] = cvtpk_bf16(p[4 * g + 2], p[4 * g + 3]);
      }
#pragma unroll
      for (int c = 0; c < 2; ++c) {
        unsigned int a0 = w[4 * c], a1 = w[4 * c + 1], b0 = w[4 * c + 2], b1 = w[4 * c + 3];
        unsigned int sa0 = __shfl_xor(a0, 32), sa1 = __shfl_xor(a1, 32);
        unsigned int sb0 = __shfl_xor(b0, 32), sb1 = __shfl_xor(b1, 32);
        union { unsigned int u[4]; bf16x8 v; } af;
        af.u[0] = hi ? sb0 : a0;   // e {0,1}
        af.u[1] = hi ? sb1 : a1;   // e {2,3}
        af.u[2] = hi ? b0  : sa0;  // e {4,5}
        af.u[3] = hi ? b1  : sa1;  // e {6,7}
        o0 = __builtin_amdgcn_mfma_f32_32x32x16_bf16(af.v, vfr[c][0], o0, 0, 0, 0);
        o1 = __builtin_amdgcn_mfma_f32_32x32x16_bf16(af.v, vfr[c][1], o1, 0, 0, 0);
      }
    };

    loadK4(0, kA);
    int t = 0;
    while (true) {
      body(t, kA, kB);
      ++t; if (t >= nt) break;
      body(t, kB, kA);
      ++t; if (t >= nt) break;
    }

    // --- epilogue: L across halves, broadcast invL to O-layout, store ---
    float Lt = Lp + __shfl_xor(Lp, 32);
    float inv = 1.0f / Lt;
#pragma unroll
    for (int r = 0; r < 16; ++r) {
      int qr = (r & 3) + 8 * (r >> 2) + 4 * hi;
      float ib = __shfl(inv, qr);
      size_t base = (size_t)(b * 2048 + qp * 32 + qr) * 1024 + h * 64;
      O[base + l31]      = f2bf(o0[r] * ib);
      O[base + 32 + l31] = f2bf(o1[r] * ib);
    }
  }
}

extern "C" void kernel_launch(void* const* d_in, const int* in_sizes, int n_in,
                              void* d_out, int out_size, void* d_ws, size_t ws_size,
                              hipStream_t stream) {
  const float* X  = (const float*)d_in[0];
  const float* Wq = (const float*)d_in[1];
  const float* Wk = (const float*)d_in[2];
  const float* Wv = (const float*)d_in[3];
  const float* Wo = (const float*)d_in[4];
  float* out = (float*)d_out;

  char* ws = (char*)d_ws;
  unsigned short* Xb    = (unsigned short*)(ws);                            // 8 MB (dead after QKV gemm)
  unsigned short* VTg   = (unsigned short*)(ws);                            // 8 MB (reuses Xb region)
  unsigned short* Wqkvb = (unsigned short*)(ws + (size_t)8  * 1024 * 1024); // 6 MB
  unsigned short* Wob   = (unsigned short*)(ws + (size_t)14 * 1024 * 1024); // 2 MB
  unsigned short* QKV   = (unsigned short*)(ws + (size_t)16 * 1024 * 1024); // 24 MB
  unsigned short* Ob    = (unsigned short*)(ws + (size_t)40 * 1024 * 1024); // 8 MB

  const int NX4 = (2 * 2048 * 1024) / 4;
  const int NW4 = (1024 * 1024) / 4;
  cast_f32_bf16<<<dim3((NX4 + 255) / 256), dim3(256), 0, stream>>>(X, Xb, NX4);
  cast_w<<<dim3((4 * NW4 + 255) / 256), dim3(256), 0, stream>>>(Wq, Wk, Wv, Wo, Wqkvb, Wob, NW4);

  gemm_bt<true ><<<dim3(32, 24), dim3(256), 0, stream>>>(Xb, Wqkvb, (void*)QKV, 4096, 3072, 1024);
  transpose_v<<<dim3(32, 32), dim3(256), 0, stream>>>(QKV, VTg);
  attn7<<<dim3(1024), dim3(64), 0, stream>>>(QKV, VTg, Ob);
  gemm_bt<false><<<dim3(32, 8), dim3(256), 0, stream>>>(Ob, Wob, (void*)out, 4096, 1024, 1024);
}

// Round 9
// 147.905 us; speedup vs baseline: 1.7599x; 1.0361x over previous
//
#include <hip/hip_runtime.h>
#include <hip/hip_bf16.h>

// MultiHeadSelfAttention: B=2, S=2048, D=1024, H=16, DK=64
// cast -> QKV gemm -> transpose V -> flash attention (swapped-QKT, 2-wave KV-split) -> out-proj gemm

typedef __attribute__((ext_vector_type(4))) float f32x4;
typedef __attribute__((ext_vector_type(16))) float f32x16;
typedef __attribute__((ext_vector_type(8))) short bf16x8;

#if defined(__has_builtin)
#if __has_builtin(__builtin_amdgcn_permlane32_swap)
#define HAVE_PL32 1
#endif
#endif

__device__ __forceinline__ unsigned short f2bf(float f) {
  unsigned int u = __float_as_uint(f);
  u += 0x7fffu + ((u >> 16) & 1u);
  return (unsigned short)(u >> 16);
}

__device__ __forceinline__ unsigned int cvtpk_bf16(float lo, float hi) {
  unsigned int r;
  asm("v_cvt_pk_bf16_f32 %0, %1, %2" : "=v"(r) : "v"(lo), "v"(hi));
  return r;
}

// max(own, partner-at-lane^32).  permlane32_swap(a,b) -> r0={a_lo,b_lo}, r1={a_hi,b_hi};
// with a=b=x: r0[l] = x[l<32 ? l : l-32], r1[l] = x[l<32 ? l+32 : l] -> max covers both halves.
__device__ __forceinline__ float plmax32(float x) {
#ifdef HAVE_PL32
  auto r = __builtin_amdgcn_permlane32_swap(__float_as_uint(x), __float_as_uint(x), false, false);
  return fmaxf(__uint_as_float(r[0]), __uint_as_float(r[1]));
#else
  return fmaxf(x, __shfl_xor(x, 32));
#endif
}

__global__ void cast_f32_bf16(const float* __restrict__ src,
                              unsigned short* __restrict__ dst, int n4) {
  int i = blockIdx.x * blockDim.x + threadIdx.x;
  if (i >= n4) return;
  float4 v = ((const float4*)src)[i];
  ushort4 o = make_ushort4(f2bf(v.x), f2bf(v.y), f2bf(v.z), f2bf(v.w));
  ((ushort4*)dst)[i] = o;
}

__global__ void cast_w(const float* __restrict__ Wq, const float* __restrict__ Wk,
                       const float* __restrict__ Wv, const float* __restrict__ Wo,
                       unsigned short* __restrict__ Wqkvb, unsigned short* __restrict__ Wob,
                       int nw4) {
  int i = blockIdx.x * blockDim.x + threadIdx.x;
  int sel = i / nw4, r = i - sel * nw4;
  if (sel >= 4) return;
  const float* src = (sel == 0) ? Wq : (sel == 1) ? Wk : (sel == 2) ? Wv : Wo;
  unsigned short* dst = (sel < 3) ? (Wqkvb + (size_t)sel * 1024 * 1024) : Wob;
  float4 v = ((const float4*)src)[r];
  ushort4 o = make_ushort4(f2bf(v.x), f2bf(v.y), f2bf(v.z), f2bf(v.w));
  ((ushort4*)dst)[r] = o;
}

typedef __attribute__((address_space(1))) const void gas_t;
typedef __attribute__((address_space(3))) void las_t;

__device__ __forceinline__ void gld_lds16(const unsigned short* g, unsigned short* l) {
  __builtin_amdgcn_global_load_lds((gas_t*)g, (las_t*)l, 16, 0, 0);
}

// C = A (M,K) * B(N,K)^T ; bf16 in, bf16 or f32 out. m97 structure.
template<bool BF16OUT>
__global__ __launch_bounds__(256)
void gemm_bt(const unsigned short* __restrict__ A, const unsigned short* __restrict__ B,
             void* __restrict__ Cv, int M, int N, int K) {
  __shared__ unsigned short As[128 * 32];
  __shared__ unsigned short Bs[128 * 32];
  const int tid = threadIdx.x;
  const int lane = tid & 63;
  const int wid = tid >> 6;
  const int wr = wid >> 1, wc = wid & 1;
  const int lr = lane & 15, lg = lane >> 4;
  const int m0 = blockIdx.x * 128, n0 = blockIdx.y * 128;

  f32x4 acc[4][4] = {};

  const int srow = tid >> 2;
  const int scol = (tid & 3) * 8;
  const unsigned short* Ag = A + (size_t)(m0 + srow) * K + scol;
  const unsigned short* Bg = B + (size_t)(n0 + srow) * K + scol;
  unsigned short* Al = &As[tid * 8];
  unsigned short* Bl = &Bs[tid * 8];

  for (int k0 = 0; k0 < K; k0 += 32) {
    gld_lds16(Ag + k0, Al);
    gld_lds16(Ag + k0 + (size_t)64 * K, Al + 2048);
    gld_lds16(Bg + k0, Bl);
    gld_lds16(Bg + k0 + (size_t)64 * K, Bl + 2048);
    asm volatile("s_waitcnt vmcnt(0)" ::: "memory");
    __syncthreads();

    bf16x8 af[4], bfr[4];
#pragma unroll
    for (int i = 0; i < 4; ++i)
      af[i] = *(const bf16x8*)&As[(wr * 64 + i * 16 + lr) * 32 + lg * 8];
#pragma unroll
    for (int j = 0; j < 4; ++j)
      bfr[j] = *(const bf16x8*)&Bs[(wc * 64 + j * 16 + lr) * 32 + lg * 8];
#pragma unroll
    for (int i = 0; i < 4; ++i)
#pragma unroll
      for (int j = 0; j < 4; ++j)
        acc[i][j] = __builtin_amdgcn_mfma_f32_16x16x32_bf16(af[i], bfr[j], acc[i][j], 0, 0, 0);
    __syncthreads();
  }

#pragma unroll
  for (int i = 0; i < 4; ++i) {
    const int row = m0 + wr * 64 + i * 16 + lg * 4;
#pragma unroll
    for (int j = 0; j < 4; ++j) {
      const int col = n0 + wc * 64 + j * 16 + lr;
#pragma unroll
      for (int r = 0; r < 4; ++r) {
        float v = acc[i][j][r];
        size_t idx = (size_t)(row + r) * N + col;
        if (BF16OUT) ((unsigned short*)Cv)[idx] = f2bf(v);
        else         ((float*)Cv)[idx] = v;
      }
    }
  }
}

// VT[(bh*64 + d)*2048 + s] = QKV[(b*2048+s)*3072 + 2048 + h*64 + d]
__global__ __launch_bounds__(256)
void transpose_v(const unsigned short* __restrict__ QKV, unsigned short* __restrict__ VT) {
  __shared__ __align__(16) unsigned short t[64 * 64];
  const int tid = threadIdx.x;
  const int bh = blockIdx.y, b = bh >> 4, h = bh & 15;
  const int s0 = blockIdx.x * 64;
#pragma unroll
  for (int it = 0; it < 2; ++it) {
    int idx = it * 256 + tid;
    int r = idx >> 3, c8 = (idx & 7) * 8;
    bf16x8 v = *(const bf16x8*)(QKV + (size_t)(b * 2048 + s0 + r) * 3072 + 2048 + h * 64 + c8);
    int sw = ((r & 7) ^ ((r >> 3) & 7)) * 8;
    *(bf16x8*)&t[r * 64 + (c8 ^ sw)] = v;
  }
  __syncthreads();
#pragma unroll
  for (int it = 0; it < 2; ++it) {
    int idx = it * 256 + tid;
    int d = idx >> 3, s8 = (idx & 7) * 8;
    unsigned short tmp[8];
#pragma unroll
    for (int j = 0; j < 8; ++j) {
      int row = s8 + j;
      int sw = ((row & 7) ^ ((row >> 3) & 7)) * 8;
      tmp[j] = t[row * 64 + ((d & ~7) ^ sw) + (d & 7)];
    }
    *(bf16x8*)(VT + (size_t)(bh * 64 + d) * 2048 + s0 + s8) = *(bf16x8*)tmp;
  }
}

// Flash attention, causal, swapped-QKT 32x32.
// Grid 1024 = 32 pairs x 32 bh (bh low bits: 4 bh/XCD, KV L2-resident).
// Block = 2 waves, SAME q-tile, split kv range: w0 [0,nt/2), w1 [nt/2,nt).
// Wave handles qp=pair then qp=63-pair; in-block split gives 2 waves/SIMD.
// P-frag assembly via permlane32_swap: swap(a,b) -> r0={a_lo,b_lo}, r1={a_hi,b_hi}.
__global__ __launch_bounds__(128)
void attn9(const unsigned short* __restrict__ QKV, const unsigned short* __restrict__ VT,
           unsigned short* __restrict__ O) {
  const int tid = threadIdx.x;
  const int w = tid >> 6;
  const int lane = tid & 63;
  const int l31 = lane & 31;
  const int hi = lane >> 5;
  const int blk = blockIdx.x;
  const int pair = blk >> 5;  // 0..31
  const int bh = blk & 31;
  const int b = bh >> 4, h = bh & 15;

  __shared__ float mbuf[32][64];     // wave1's O partial (row q, col d)
  __shared__ float mML[2][2][32];    // [wave][M/L][row]

  const unsigned short* Qb = QKV + (size_t)b * 2048 * 3072 + h * 64;
  const unsigned short* Kb = QKV + (size_t)b * 2048 * 3072 + 1024 + h * 64;
  const unsigned short* Vt = VT + (size_t)bh * 64 * 2048;

  const float sc = 0.125f * 1.44269504088896f;  // 1/sqrt(64) * log2(e)

  for (int ph = 0; ph < 2; ++ph) {
    const int qp = ph ? (63 - pair) : pair;
    const int nt = qp + 1;          // kv tiles of 32
    const int tmid = nt >> 1;
    const int t0 = w ? tmid : 0;
    const int t1 = w ? nt : tmid;   // w0: floor(nt/2) tiles, w1: ceil (owns diagonal)

    bf16x8 qf[4];
#pragma unroll
    for (int i = 0; i < 4; ++i)
      qf[i] = *(const bf16x8*)(Qb + (size_t)(qp * 32 + l31) * 3072 + 16 * i + 8 * hi);

    f32x16 o0, o1;
#pragma unroll
    for (int r = 0; r < 16; ++r) { o0[r] = 0.f; o1[r] = 0.f; }
    float M = -1e30f, Lp = 0.f;

    bf16x8 kA[4], kB[4], vA[2][2], vB[2][2];

    auto loadK4 = [&](int t, bf16x8 (&kd)[4]) {
#pragma unroll
      for (int i = 0; i < 4; ++i)
        kd[i] = *(const bf16x8*)(Kb + (size_t)(t * 32 + l31) * 3072 + 16 * i + 8 * hi);
    };
    auto loadV4 = [&](int t, bf16x8 (&vd)[2][2]) {
#pragma unroll
      for (int c = 0; c < 2; ++c)
#pragma unroll
        for (int dh = 0; dh < 2; ++dh)
          vd[c][dh] = *(const bf16x8*)(Vt + (size_t)(dh * 32 + l31) * 2048 + t * 32 + c * 16 + 8 * hi);
    };

    auto body = [&](int t, bf16x8 (&kcur)[4], bf16x8 (&knxt)[4],
                    bf16x8 (&vcur)[2][2], bf16x8 (&vnxt)[2][2]) {
      // --- S^T = K Q^T (32kv x 32q), lane owns q-col l31 ---
      f32x16 st;
#pragma unroll
      for (int r = 0; r < 16; ++r) st[r] = 0.f;
#pragma unroll
      for (int i = 0; i < 4; ++i)
        st = __builtin_amdgcn_mfma_f32_32x32x16_bf16(kcur[i], qf[i], st, 0, 0, 0);

      // --- prefetch next K and V (off-chain) ---
      if (t + 1 < t1) { loadK4(t + 1, knxt); loadV4(t + 1, vnxt); }

      // --- scale (+ causal mask on diagonal), log2 domain ---
      float x[16];
#pragma unroll
      for (int r = 0; r < 16; ++r) x[r] = st[r] * sc;
      if (t == nt - 1) {
#pragma unroll
        for (int r = 0; r < 16; ++r) {
          int kvi = (r & 3) + 8 * (r >> 2) + 4 * hi;
          if (kvi > l31) x[r] = -3.0e38f;
        }
      }

      // --- row max (in-register + cross-half) ---
      float mx = x[0];
#pragma unroll
      for (int r = 1; r < 16; ++r) mx = fmaxf(mx, x[r]);
      mx = plmax32(mx);

      // --- defer-max (THR=8): rescale only when max grows ---
      bool chg = mx > M + 8.0f;
      if (__any(chg)) {
        float Mn = chg ? mx : M;
        float ef = exp2f(M - Mn);
        M = Mn;
        Lp *= ef;
#pragma unroll
        for (int r = 0; r < 16; ++r) {
          int qr = (r & 3) + 8 * (r >> 2) + 4 * hi;
          float efb = __shfl(ef, qr);
          o0[r] *= efb;
          o1[r] *= efb;
        }
      }

      // --- P = exp2(x - M); lane-partial L ---
      float p[16];
      float rs = 0.f;
#pragma unroll
      for (int r = 0; r < 16; ++r) {
        p[r] = exp2f(x[r] - M);
        rs += p[r];
      }
      Lp += rs;

      // --- pack P to bf16; assemble PV A-frags ---
      // pw[2g]/pw[2g+1] hold kv {base,base+1}/{base+2,base+3}, base=8*(g&1?...)...
      // af.u[0] needs {pw0_lo, pw2_lo(partner)} = swap(pw0,pw2)[0]; af.u[2] = [1].
      unsigned int pw[8];
#pragma unroll
      for (int g = 0; g < 4; ++g) {
        pw[2 * g]     = cvtpk_bf16(p[4 * g],     p[4 * g + 1]);
        pw[2 * g + 1] = cvtpk_bf16(p[4 * g + 2], p[4 * g + 3]);
      }
#pragma unroll
      for (int c = 0; c < 2; ++c) {
        unsigned int a0 = pw[4 * c], a1 = pw[4 * c + 1];
        unsigned int b0 = pw[4 * c + 2], b1 = pw[4 * c + 3];
        union { unsigned int u[4]; bf16x8 v; } af;
#ifdef HAVE_PL32
        auto r0 = __builtin_amdgcn_permlane32_swap(a0, b0, false, false);
        auto r1 = __builtin_amdgcn_permlane32_swap(a1, b1, false, false);
        af.u[0] = r0[0]; af.u[2] = r0[1];
        af.u[1] = r1[0]; af.u[3] = r1[1];
#else
        unsigned int sa0 = __shfl_xor(a0, 32), sa1 = __shfl_xor(a1, 32);
        unsigned int sb0 = __shfl_xor(b0, 32), sb1 = __shfl_xor(b1, 32);
        af.u[0] = hi ? sb0 : a0;
        af.u[1] = hi ? sb1 : a1;
        af.u[2] = hi ? b0  : sa0;
        af.u[3] = hi ? b1  : sa1;
#endif
        o0 = __builtin_amdgcn_mfma_f32_32x32x16_bf16(af.v, vcur[c][0], o0, 0, 0, 0);
        o1 = __builtin_amdgcn_mfma_f32_32x32x16_bf16(af.v, vcur[c][1], o1, 0, 0, 0);
      }
    };

    if (t0 < t1) {
      loadK4(t0, kA);
      loadV4(t0, vA);
      int t = t0;
      while (true) {
        body(t, kA, kB, vA, vB);
        ++t; if (t >= t1) break;
        body(t, kB, kA, vB, vA);
        ++t; if (t >= t1) break;
      }
    }

    // --- merge the two kv-chunks via LDS ---
    float Ltot = Lp + __shfl_xor(Lp, 32);
    if (w == 1) {
      if (!hi) { mML[1][0][l31] = M; mML[1][1][l31] = Ltot; }
#pragma unroll
      for (int r = 0; r < 16; ++r) {
        int qr = (r & 3) + 8 * (r >> 2) + 4 * hi;
        mbuf[qr][l31]      = o0[r];
        mbuf[qr][32 + l31] = o1[r];
      }
    } else {
      if (!hi) { mML[0][0][l31] = M; mML[0][1][l31] = Ltot; }
    }
    __syncthreads();
    if (w == 0) {
#pragma unroll
      for (int r = 0; r < 16; ++r) {
        int qr = (r & 3) + 8 * (r >> 2) + 4 * hi;
        float Ma = mML[0][0][qr], La = mML[0][1][qr];
        float Mb = mML[1][0][qr], Lb = mML[1][1][qr];
        float Mx = fmaxf(Ma, Mb);
        float ea = exp2f(Ma - Mx), eb = exp2f(Mb - Mx);
        float inv = 1.0f / (La * ea + Lb * eb);
        float v0 = (o0[r] * ea + mbuf[qr][l31]      * eb) * inv;
        float v1 = (o1[r] * ea + mbuf[qr][32 + l31] * eb) * inv;
        size_t base = (size_t)(b * 2048 + qp * 32 + qr) * 1024 + h * 64;
        O[base + l31]      = f2bf(v0);
        O[base + 32 + l31] = f2bf(v1);
      }
    }
    __syncthreads();  // LDS safe for next phase
  }
}

extern "C" void kernel_launch(void* const* d_in, const int* in_sizes, int n_in,
                              void* d_out, int out_size, void* d_ws, size_t ws_size,
                              hipStream_t stream) {
  const float* X  = (const float*)d_in[0];
  const float* Wq = (const float*)d_in[1];
  const float* Wk = (const float*)d_in[2];
  const float* Wv = (const float*)d_in[3];
  const float* Wo = (const float*)d_in[4];
  float* out = (float*)d_out;

  char* ws = (char*)d_ws;
  unsigned short* Xb    = (unsigned short*)(ws);                            // 8 MB (dead after QKV gemm)
  unsigned short* VTg   = (unsigned short*)(ws);                            // 8 MB (reuses Xb region)
  unsigned short* Wqkvb = (unsigned short*)(ws + (size_t)8  * 1024 * 1024); // 6 MB
  unsigned short* Wob   = (unsigned short*)(ws + (size_t)14 * 1024 * 1024); // 2 MB
  unsigned short* QKV   = (unsigned short*)(ws + (size_t)16 * 1024 * 1024); // 24 MB
  unsigned short* Ob    = (unsigned short*)(ws + (size_t)40 * 1024 * 1024); // 8 MB

  const int NX4 = (2 * 2048 * 1024) / 4;
  const int NW4 = (1024 * 1024) / 4;
  cast_f32_bf16<<<dim3((NX4 + 255) / 256), dim3(256), 0, stream>>>(X, Xb, NX4);
  cast_w<<<dim3((4 * NW4 + 255) / 256), dim3(256), 0, stream>>>(Wq, Wk, Wv, Wo, Wqkvb, Wob, NW4);

  gemm_bt<true ><<<dim3(32, 24), dim3(256), 0, stream>>>(Xb, Wqkvb, (void*)QKV, 4096, 3072, 1024);
  transpose_v<<<dim3(32, 32), dim3(256), 0, stream>>>(QKV, VTg);
  attn9<<<dim3(1024), dim3(128), 0, stream>>>(QKV, VTg, Ob);
  gemm_bt<false><<<dim3(32, 8), dim3(256), 0, stream>>>(Ob, Wob, (void*)out, 4096, 1024, 1024);
}

// Round 10
// 147.715 us; speedup vs baseline: 1.7621x; 1.0013x over previous
//
#include <hip/hip_runtime.h>
#include <hip/hip_bf16.h>

// MultiHeadSelfAttention: B=2, S=2048, D=1024, H=16, DK=64
// cast -> QKV gemm -> transpose V -> flash attention (swapped-QKT, 2-stage pipelined) -> out-proj gemm

typedef __attribute__((ext_vector_type(4))) float f32x4;
typedef __attribute__((ext_vector_type(16))) float f32x16;
typedef __attribute__((ext_vector_type(8))) short bf16x8;

#if defined(__has_builtin)
#if __has_builtin(__builtin_amdgcn_permlane32_swap)
#define HAVE_PL32 1
#endif
#endif

__device__ __forceinline__ unsigned short f2bf(float f) {
  unsigned int u = __float_as_uint(f);
  u += 0x7fffu + ((u >> 16) & 1u);
  return (unsigned short)(u >> 16);
}

__device__ __forceinline__ unsigned int cvtpk_bf16(float lo, float hi) {
  unsigned int r;
  asm("v_cvt_pk_bf16_f32 %0, %1, %2" : "=v"(r) : "v"(lo), "v"(hi));
  return r;
}

// max(own, partner-at-lane^32): swap(a,b) -> r0={a_lo,b_lo}, r1={a_hi,b_hi}
__device__ __forceinline__ float plmax32(float x) {
#ifdef HAVE_PL32
  auto r = __builtin_amdgcn_permlane32_swap(__float_as_uint(x), __float_as_uint(x), false, false);
  return fmaxf(__uint_as_float(r[0]), __uint_as_float(r[1]));
#else
  return fmaxf(x, __shfl_xor(x, 32));
#endif
}

__global__ void cast_f32_bf16(const float* __restrict__ src,
                              unsigned short* __restrict__ dst, int n4) {
  int i = blockIdx.x * blockDim.x + threadIdx.x;
  if (i >= n4) return;
  float4 v = ((const float4*)src)[i];
  ushort4 o = make_ushort4(f2bf(v.x), f2bf(v.y), f2bf(v.z), f2bf(v.w));
  ((ushort4*)dst)[i] = o;
}

__global__ void cast_w(const float* __restrict__ Wq, const float* __restrict__ Wk,
                       const float* __restrict__ Wv, const float* __restrict__ Wo,
                       unsigned short* __restrict__ Wqkvb, unsigned short* __restrict__ Wob,
                       int nw4) {
  int i = blockIdx.x * blockDim.x + threadIdx.x;
  int sel = i / nw4, r = i - sel * nw4;
  if (sel >= 4) return;
  const float* src = (sel == 0) ? Wq : (sel == 1) ? Wk : (sel == 2) ? Wv : Wo;
  unsigned short* dst = (sel < 3) ? (Wqkvb + (size_t)sel * 1024 * 1024) : Wob;
  float4 v = ((const float4*)src)[r];
  ushort4 o = make_ushort4(f2bf(v.x), f2bf(v.y), f2bf(v.z), f2bf(v.w));
  ((ushort4*)dst)[r] = o;
}

typedef __attribute__((address_space(1))) const void gas_t;
typedef __attribute__((address_space(3))) void las_t;

__device__ __forceinline__ void gld_lds16(const unsigned short* g, unsigned short* l) {
  __builtin_amdgcn_global_load_lds((gas_t*)g, (las_t*)l, 16, 0, 0);
}

// C = A (M,K) * B(N,K)^T ; bf16 in, bf16 or f32 out. m97 structure.
template<bool BF16OUT>
__global__ __launch_bounds__(256)
void gemm_bt(const unsigned short* __restrict__ A, const unsigned short* __restrict__ B,
             void* __restrict__ Cv, int M, int N, int K) {
  __shared__ unsigned short As[128 * 32];
  __shared__ unsigned short Bs[128 * 32];
  const int tid = threadIdx.x;
  const int lane = tid & 63;
  const int wid = tid >> 6;
  const int wr = wid >> 1, wc = wid & 1;
  const int lr = lane & 15, lg = lane >> 4;
  const int m0 = blockIdx.x * 128, n0 = blockIdx.y * 128;

  f32x4 acc[4][4] = {};

  const int srow = tid >> 2;
  const int scol = (tid & 3) * 8;
  const unsigned short* Ag = A + (size_t)(m0 + srow) * K + scol;
  const unsigned short* Bg = B + (size_t)(n0 + srow) * K + scol;
  unsigned short* Al = &As[tid * 8];
  unsigned short* Bl = &Bs[tid * 8];

  for (int k0 = 0; k0 < K; k0 += 32) {
    gld_lds16(Ag + k0, Al);
    gld_lds16(Ag + k0 + (size_t)64 * K, Al + 2048);
    gld_lds16(Bg + k0, Bl);
    gld_lds16(Bg + k0 + (size_t)64 * K, Bl + 2048);
    asm volatile("s_waitcnt vmcnt(0)" ::: "memory");
    __syncthreads();

    bf16x8 af[4], bfr[4];
#pragma unroll
    for (int i = 0; i < 4; ++i)
      af[i] = *(const bf16x8*)&As[(wr * 64 + i * 16 + lr) * 32 + lg * 8];
#pragma unroll
    for (int j = 0; j < 4; ++j)
      bfr[j] = *(const bf16x8*)&Bs[(wc * 64 + j * 16 + lr) * 32 + lg * 8];
#pragma unroll
    for (int i = 0; i < 4; ++i)
#pragma unroll
      for (int j = 0; j < 4; ++j)
        acc[i][j] = __builtin_amdgcn_mfma_f32_16x16x32_bf16(af[i], bfr[j], acc[i][j], 0, 0, 0);
    __syncthreads();
  }

#pragma unroll
  for (int i = 0; i < 4; ++i) {
    const int row = m0 + wr * 64 + i * 16 + lg * 4;
#pragma unroll
    for (int j = 0; j < 4; ++j) {
      const int col = n0 + wc * 64 + j * 16 + lr;
#pragma unroll
      for (int r = 0; r < 4; ++r) {
        float v = acc[i][j][r];
        size_t idx = (size_t)(row + r) * N + col;
        if (BF16OUT) ((unsigned short*)Cv)[idx] = f2bf(v);
        else         ((float*)Cv)[idx] = v;
      }
    }
  }
}

// VT[(bh*64 + d)*2048 + s] = QKV[(b*2048+s)*3072 + 2048 + h*64 + d]
__global__ __launch_bounds__(256)
void transpose_v(const unsigned short* __restrict__ QKV, unsigned short* __restrict__ VT) {
  __shared__ __align__(16) unsigned short t[64 * 64];
  const int tid = threadIdx.x;
  const int bh = blockIdx.y, b = bh >> 4, h = bh & 15;
  const int s0 = blockIdx.x * 64;
#pragma unroll
  for (int it = 0; it < 2; ++it) {
    int idx = it * 256 + tid;
    int r = idx >> 3, c8 = (idx & 7) * 8;
    bf16x8 v = *(const bf16x8*)(QKV + (size_t)(b * 2048 + s0 + r) * 3072 + 2048 + h * 64 + c8);
    int sw = ((r & 7) ^ ((r >> 3) & 7)) * 8;
    *(bf16x8*)&t[r * 64 + (c8 ^ sw)] = v;
  }
  __syncthreads();
#pragma unroll
  for (int it = 0; it < 2; ++it) {
    int idx = it * 256 + tid;
    int d = idx >> 3, s8 = (idx & 7) * 8;
    unsigned short tmp[8];
#pragma unroll
    for (int j = 0; j < 8; ++j) {
      int row = s8 + j;
      int sw = ((row & 7) ^ ((row >> 3) & 7)) * 8;
      tmp[j] = t[row * 64 + ((d & ~7) ^ sw) + (d & 7)];
    }
    *(bf16x8*)(VT + (size_t)(bh * 64 + d) * 2048 + s0 + s8) = *(bf16x8*)tmp;
  }
}

// Flash attention, causal, swapped-QKT 32x32, 2-STAGE SOFTWARE PIPELINE:
// body issues QK^T(t+1) MFMAs first, then softmax+PV(t) -> MFMA pipe and
// VALU/TRANS overlap (T15 mechanism); setprio(1) around MFMA clusters (T5).
// Grid 1024 = 32 pairs x 32 bh; block = 2 waves splitting the kv range.
__global__ __launch_bounds__(128, 2)
void attn10(const unsigned short* __restrict__ QKV, const unsigned short* __restrict__ VT,
            unsigned short* __restrict__ O) {
  const int tid = threadIdx.x;
  const int w = tid >> 6;
  const int lane = tid & 63;
  const int l31 = lane & 31;
  const int hi = lane >> 5;
  const int blk = blockIdx.x;
  const int pair = blk >> 5;  // 0..31
  const int bh = blk & 31;
  const int b = bh >> 4, h = bh & 15;

  __shared__ float mbuf[32][64];     // wave1's O partial (row q, col d)
  __shared__ float mML[2][2][32];    // [wave][M/L][row]

  const unsigned short* Qb = QKV + (size_t)b * 2048 * 3072 + h * 64;
  const unsigned short* Kb = QKV + (size_t)b * 2048 * 3072 + 1024 + h * 64;
  const unsigned short* Vt = VT + (size_t)bh * 64 * 2048;

  const float sc = 0.125f * 1.44269504088896f;  // 1/sqrt(64) * log2(e)

  for (int ph = 0; ph < 2; ++ph) {
    const int qp = ph ? (63 - pair) : pair;
    const int nt = qp + 1;          // kv tiles of 32
    const int tmid = nt >> 1;
    const int t0 = w ? tmid : 0;
    const int t1 = w ? nt : tmid;

    bf16x8 qf[4];
#pragma unroll
    for (int i = 0; i < 4; ++i)
      qf[i] = *(const bf16x8*)(Qb + (size_t)(qp * 32 + l31) * 3072 + 16 * i + 8 * hi);

    f32x16 o0, o1;
#pragma unroll
    for (int r = 0; r < 16; ++r) { o0[r] = 0.f; o1[r] = 0.f; }
    float M = -1e30f, Lp = 0.f;

    bf16x8 kA[4], kB[4], vA[2][2], vB[2][2];
    f32x16 stA, stB;

    auto loadK4 = [&](int t, bf16x8 (&kd)[4]) {
#pragma unroll
      for (int i = 0; i < 4; ++i)
        kd[i] = *(const bf16x8*)(Kb + (size_t)(t * 32 + l31) * 3072 + 16 * i + 8 * hi);
    };
    auto loadV4 = [&](int t, bf16x8 (&vd)[2][2]) {
#pragma unroll
      for (int c = 0; c < 2; ++c)
#pragma unroll
        for (int dh = 0; dh < 2; ++dh)
          vd[c][dh] = *(const bf16x8*)(Vt + (size_t)(dh * 32 + l31) * 2048 + t * 32 + c * 16 + 8 * hi);
    };
    auto QKT = [&](bf16x8 (&k)[4], f32x16& st) {
#pragma unroll
      for (int r = 0; r < 16; ++r) st[r] = 0.f;
      __builtin_amdgcn_s_setprio(1);
#pragma unroll
      for (int i = 0; i < 4; ++i)
        st = __builtin_amdgcn_mfma_f32_32x32x16_bf16(k[i], qf[i], st, 0, 0, 0);
      __builtin_amdgcn_s_setprio(0);
    };
    // softmax(t) + PV(t) on a finished score tile
    auto SMPV = [&](f32x16& st, int t, bf16x8 (&vc)[2][2]) {
      float x[16];
#pragma unroll
      for (int r = 0; r < 16; ++r) x[r] = st[r] * sc;
      if (t == nt - 1) {
#pragma unroll
        for (int r = 0; r < 16; ++r) {
          int kvi = (r & 3) + 8 * (r >> 2) + 4 * hi;
          if (kvi > l31) x[r] = -3.0e38f;
        }
      }
      float mx = x[0];
#pragma unroll
      for (int r = 1; r < 16; ++r) mx = fmaxf(mx, x[r]);
      mx = plmax32(mx);

      bool chg = mx > M + 8.0f;
      if (__any(chg)) {
        float Mn = chg ? mx : M;
        float ef = exp2f(M - Mn);
        M = Mn;
        Lp *= ef;
#pragma unroll
        for (int r = 0; r < 16; ++r) {
          int qr = (r & 3) + 8 * (r >> 2) + 4 * hi;
          float efb = __shfl(ef, qr);
          o0[r] *= efb;
          o1[r] *= efb;
        }
      }
      float p[16];
      float rs = 0.f;
#pragma unroll
      for (int r = 0; r < 16; ++r) {
        p[r] = exp2f(x[r] - M);
        rs += p[r];
      }
      Lp += rs;

      unsigned int pw[8];
#pragma unroll
      for (int g = 0; g < 4; ++g) {
        pw[2 * g]     = cvtpk_bf16(p[4 * g],     p[4 * g + 1]);
        pw[2 * g + 1] = cvtpk_bf16(p[4 * g + 2], p[4 * g + 3]);
      }
#pragma unroll
      for (int c = 0; c < 2; ++c) {
        unsigned int a0 = pw[4 * c], a1 = pw[4 * c + 1];
        unsigned int b0 = pw[4 * c + 2], b1 = pw[4 * c + 3];
        union { unsigned int u[4]; bf16x8 v; } af;
#ifdef HAVE_PL32
        auto r0 = __builtin_amdgcn_permlane32_swap(a0, b0, false, false);
        auto r1 = __builtin_amdgcn_permlane32_swap(a1, b1, false, false);
        af.u[0] = r0[0]; af.u[2] = r0[1];
        af.u[1] = r1[0]; af.u[3] = r1[1];
#else
        unsigned int sa0 = __shfl_xor(a0, 32), sa1 = __shfl_xor(a1, 32);
        unsigned int sb0 = __shfl_xor(b0, 32), sb1 = __shfl_xor(b1, 32);
        af.u[0] = hi ? sb0 : a0;
        af.u[1] = hi ? sb1 : a1;
        af.u[2] = hi ? b0  : sa0;
        af.u[3] = hi ? b1  : sa1;
#endif
        __builtin_amdgcn_s_setprio(1);
        o0 = __builtin_amdgcn_mfma_f32_32x32x16_bf16(af.v, vc[c][0], o0, 0, 0, 0);
        o1 = __builtin_amdgcn_mfma_f32_32x32x16_bf16(af.v, vc[c][1], o1, 0, 0, 0);
        __builtin_amdgcn_s_setprio(0);
      }
    };

    if (t0 < t1) {
      // prologue: fill stage A, prefetch stage B
      loadK4(t0, kA);
      loadV4(t0, vA);
      QKT(kA, stA);
      if (t0 + 1 < t1) { loadK4(t0 + 1, kB); loadV4(t0 + 1, vB); }
      int t = t0;
      while (true) {
        // even: start t+1 on MFMA pipe, finish t on VALU, refill slot A
        if (t + 1 < t1) QKT(kB, stB);
        SMPV(stA, t, vA);
        if (t + 2 < t1) { loadK4(t + 2, kA); loadV4(t + 2, vA); }
        ++t; if (t >= t1) break;
        // odd: mirror with swapped slots
        if (t + 1 < t1) QKT(kA, stA);
        SMPV(stB, t, vB);
        if (t + 2 < t1) { loadK4(t + 2, kB); loadV4(t + 2, vB); }
        ++t; if (t >= t1) break;
      }
    }

    // --- merge the two kv-chunks via LDS ---
    float Ltot = Lp + __shfl_xor(Lp, 32);
    if (w == 1) {
      if (!hi) { mML[1][0][l31] = M; mML[1][1][l31] = Ltot; }
#pragma unroll
      for (int r = 0; r < 16; ++r) {
        int qr = (r & 3) + 8 * (r >> 2) + 4 * hi;
        mbuf[qr][l31]      = o0[r];
        mbuf[qr][32 + l31] = o1[r];
      }
    } else {
      if (!hi) { mML[0][0][l31] = M; mML[0][1][l31] = Ltot; }
    }
    __syncthreads();
    if (w == 0) {
#pragma unroll
      for (int r = 0; r < 16; ++r) {
        int qr = (r & 3) + 8 * (r >> 2) + 4 * hi;
        float Ma = mML[0][0][qr], La = mML[0][1][qr];
        float Mb = mML[1][0][qr], Lb = mML[1][1][qr];
        float Mx = fmaxf(Ma, Mb);
        float ea = exp2f(Ma - Mx), eb = exp2f(Mb - Mx);
        float inv = 1.0f / (La * ea + Lb * eb);
        float v0 = (o0[r] * ea + mbuf[qr][l31]      * eb) * inv;
        float v1 = (o1[r] * ea + mbuf[qr][32 + l31] * eb) * inv;
        size_t base = (size_t)(b * 2048 + qp * 32 + qr) * 1024 + h * 64;
        O[base + l31]      = f2bf(v0);
        O[base + 32 + l31] = f2bf(v1);
      }
    }
    __syncthreads();  // LDS safe for next phase
  }
}

extern "C" void kernel_launch(void* const* d_in, const int* in_sizes, int n_in,
                              void* d_out, int out_size, void* d_ws, size_t ws_size,
                              hipStream_t stream) {
  const float* X  = (const float*)d_in[0];
  const float* Wq = (const float*)d_in[1];
  const float* Wk = (const float*)d_in[2];
  const float* Wv = (const float*)d_in[3];
  const float* Wo = (const float*)d_in[4];
  float* out = (float*)d_out;

  char* ws = (char*)d_ws;
  unsigned short* Xb    = (unsigned short*)(ws);                            // 8 MB (dead after QKV gemm)
  unsigned short* VTg   = (unsigned short*)(ws);                            // 8 MB (reuses Xb region)
  unsigned short* Wqkvb = (unsigned short*)(ws + (size_t)8  * 1024 * 1024); // 6 MB
  unsigned short* Wob   = (unsigned short*)(ws + (size_t)14 * 1024 * 1024); // 2 MB
  unsigned short* QKV   = (unsigned short*)(ws + (size_t)16 * 1024 * 1024); // 24 MB
  unsigned short* Ob    = (unsigned short*)(ws + (size_t)40 * 1024 * 1024); // 8 MB

  const int NX4 = (2 * 2048 * 1024) / 4;
  const int NW4 = (1024 * 1024) / 4;
  cast_f32_bf16<<<dim3((NX4 + 255) / 256), dim3(256), 0, stream>>>(X, Xb, NX4);
  cast_w<<<dim3((4 * NW4 + 255) / 256), dim3(256), 0, stream>>>(Wq, Wk, Wv, Wo, Wqkvb, Wob, NW4);

  gemm_bt<true ><<<dim3(32, 24), dim3(256), 0, stream>>>(Xb, Wqkvb, (void*)QKV, 4096, 3072, 1024);
  transpose_v<<<dim3(32, 32), dim3(256), 0, stream>>>(QKV, VTg);
  attn10<<<dim3(1024), dim3(128), 0, stream>>>(QKV, VTg, Ob);
  gemm_bt<false><<<dim3(32, 8), dim3(256), 0, stream>>>(Ob, Wob, (void*)out, 4096, 1024, 1024);
}